// Round 6
// baseline (218.628 us; speedup 1.0000x reference)
//
#include <hip/hip_runtime.h>

#define NB 4
#define QLEN 2048
#define KLEN 2048
#define QDIM 512
#define EMBED 1024
#define HEADS 16
#define HD 64

typedef __bf16 bf16x8 __attribute__((ext_vector_type(8)));
typedef float f32x4 __attribute__((ext_vector_type(4)));
typedef float f32x16 __attribute__((ext_vector_type(16)));

#define CLOG 0.18033688011112042f   // 0.125 * log2(e), folded into Wq

// guaranteed-cheap exp2
__device__ __forceinline__ float fexp2(float x) {
#if __has_builtin(__builtin_amdgcn_exp2f)
    return __builtin_amdgcn_exp2f(x);
#else
    float r;
    asm("v_exp_f32 %0, %1\n\ts_nop 1" : "=v"(r) : "v"(x));
    return r;
#endif
}

// pack two f32 into packed bf16 (RNE)
#if __has_builtin(__builtin_amdgcn_cvt_pk_bf16_f32)
typedef __bf16 bf16x2_t __attribute__((ext_vector_type(2)));
__device__ __forceinline__ unsigned pack_bf16(float a, float b) {
    bf16x2_t r = __builtin_amdgcn_cvt_pk_bf16_f32(a, b);
    return __builtin_bit_cast(unsigned, r);
}
#else
__device__ __forceinline__ unsigned pack_bf16(float a, float b) {
    unsigned ua = __builtin_bit_cast(unsigned, a);
    unsigned ub = __builtin_bit_cast(unsigned, b);
    ua = (ua + 0x7FFFu + ((ua >> 16) & 1u)) >> 16;
    ub = (ub + 0x7FFFu + ((ub >> 16) & 1u)) & 0xFFFF0000u;
    return ua | ub;
}
#endif

#if __has_builtin(__builtin_amdgcn_sched_barrier)
#define SCHED_FENCE() __builtin_amdgcn_sched_barrier(0)
#else
#define SCHED_FENCE()
#endif

// async global->LDS 16B: dest = wave-uniform base + lane*16
__device__ __forceinline__ void dma16(const void* g, void* l) {
    __builtin_amdgcn_global_load_lds(
        (const __attribute__((address_space(1))) void*)g,
        (__attribute__((address_space(3))) void*)l, 16, 0, 0);
}

// ---------------------------------------------------------------------------
// prep: bf16 casts (q,k,v) + W transposes + mask->float. 4612 blocks x 256.
// ---------------------------------------------------------------------------
__global__ __launch_bounds__(256) void prep(const float* __restrict__ q,
                                            const float* __restrict__ k,
                                            const float* __restrict__ v,
                                            const float* __restrict__ Wq,
                                            const float* __restrict__ Wk,
                                            const float* __restrict__ Wv,
                                            const int* __restrict__ mask,
                                            __bf16* __restrict__ qd,
                                            __bf16* __restrict__ kd,
                                            __bf16* __restrict__ vd,
                                            __bf16* __restrict__ WtQ,
                                            __bf16* __restrict__ WtK,
                                            __bf16* __restrict__ WtV,
                                            float* __restrict__ mskf) {
    __shared__ float tile[32][33];
    int b = blockIdx.x, tid = threadIdx.x;
    if (b < 3072) {
        const float* src; __bf16* dst; int cb;
        if (b < 2048)      { src = q; dst = qd; cb = b; }
        else if (b < 2560) { src = k; dst = kd; cb = b - 2048; }
        else               { src = v; dst = vd; cb = b - 2560; }
        int i = (cb * 256 + tid) * 8;
        float4 a0 = *(const float4*)&src[i];
        float4 a1 = *(const float4*)&src[i + 4];
        bf16x8 o;
        o[0] = (__bf16)a0.x; o[1] = (__bf16)a0.y; o[2] = (__bf16)a0.z; o[3] = (__bf16)a0.w;
        o[4] = (__bf16)a1.x; o[5] = (__bf16)a1.y; o[6] = (__bf16)a1.z; o[7] = (__bf16)a1.w;
        *(bf16x8*)&dst[i] = o;
    } else if (b < 4608) {
        int tb = b - 3072;
        int which = tb >> 9, r = tb & 511;
        const float* src = (which == 0) ? Wq : (which == 1) ? Wk : Wv;
        __bf16* dst = (which == 0) ? WtQ : (which == 1) ? WtK : WtV;
        float scale = (which == 0) ? CLOG : 1.0f;
        int e0 = (r & 31) * 32, c0 = (r >> 5) * 32;
        int tx = tid & 31, ty = tid >> 5;  // 32 x 8
        for (int i = 0; i < 4; i++)
            tile[ty + 8 * i][tx] = src[(c0 + ty + 8 * i) * EMBED + e0 + tx];
        __syncthreads();
        for (int i = 0; i < 4; i++)
            dst[(e0 + ty + 8 * i) * QDIM + c0 + tx] = (__bf16)(tile[tx][ty + 8 * i] * scale);
    } else {
        int i = ((b - 4608) * 256 + tid) * 8;
        int4 ma = *(const int4*)&mask[i];
        int4 mb = *(const int4*)&mask[i + 4];
        f32x4 fa, fb;
        fa[0] = ma.x ? 1.f : 0.f; fa[1] = ma.y ? 1.f : 0.f;
        fa[2] = ma.z ? 1.f : 0.f; fa[3] = ma.w ? 1.f : 0.f;
        fb[0] = mb.x ? 1.f : 0.f; fb[1] = mb.y ? 1.f : 0.f;
        fb[2] = mb.z ? 1.f : 0.f; fb[3] = mb.w ? 1.f : 0.f;
        *(f32x4*)&mskf[i] = fa;
        *(f32x4*)&mskf[i + 4] = fb;
    }
}

// ---------------------------------------------------------------------------
// 128x128-tile GEMM body, double-buffered DMA staging, BK=32, 2x2 wave grid
// ---------------------------------------------------------------------------
__device__ __forceinline__ void gemm_compute(const __bf16* As, const __bf16* Bs,
                                             int wr, int wc, int r16, int qq,
                                             f32x4 (&acc)[4][4]) {
    bf16x8 af[4], bq[4];
#pragma unroll
    for (int i = 0; i < 4; i++)
        af[i] = *(const bf16x8*)&As[(wr * 64 + i * 16 + r16) * 32 + qq * 8];
#pragma unroll
    for (int j = 0; j < 4; j++)
        bq[j] = *(const bf16x8*)&Bs[(wc * 64 + j * 16 + r16) * 32 + qq * 8];
#pragma unroll
    for (int i = 0; i < 4; i++)
#pragma unroll
        for (int j = 0; j < 4; j++)
            acc[i][j] = __builtin_amdgcn_mfma_f32_16x16x32_bf16(af[i], bq[j], acc[i][j], 0, 0, 0);
}

__device__ __forceinline__ void gemm128(const __bf16* __restrict__ A,
                                        const __bf16* __restrict__ Bt,
                                        __bf16* As0, __bf16* As1,
                                        __bf16* Bs0, __bf16* Bs1,
                                        int row0, int col0, f32x4 (&acc)[4][4]) {
    int tid = threadIdx.x, wave = tid >> 6, lane = tid & 63;
    int r16 = lane & 15, qq = lane >> 4;
    int wr = wave >> 1, wc = wave & 1;
    const __bf16* agp1 = A + (size_t)(row0 + (tid >> 2)) * QDIM + (tid & 3) * 8;
    const __bf16* agp2 = A + (size_t)(row0 + 64 + (tid >> 2)) * QDIM + (tid & 3) * 8;
    const __bf16* bgp1 = Bt + (size_t)(col0 + (tid >> 2)) * QDIM + (tid & 3) * 8;
    const __bf16* bgp2 = Bt + (size_t)(col0 + 64 + (tid >> 2)) * QDIM + (tid & 3) * 8;
    __bf16 *a0a = &As0[wave * 512], *a0b = &As0[2048 + wave * 512];
    __bf16 *a1a = &As1[wave * 512], *a1b = &As1[2048 + wave * 512];
    __bf16 *b0a = &Bs0[wave * 512], *b0b = &Bs0[2048 + wave * 512];
    __bf16 *b1a = &Bs1[wave * 512], *b1b = &Bs1[2048 + wave * 512];

    dma16(agp1, a0a); dma16(agp2, a0b);
    dma16(bgp1, b0a); dma16(bgp2, b0b);
    agp1 += 32; agp2 += 32; bgp1 += 32; bgp2 += 32;
    __syncthreads();

    for (int t = 0; t < 16; t += 2) {
        dma16(agp1, a1a); dma16(agp2, a1b);
        dma16(bgp1, b1a); dma16(bgp2, b1b);
        agp1 += 32; agp2 += 32; bgp1 += 32; bgp2 += 32;
        SCHED_FENCE();
        gemm_compute(As0, Bs0, wr, wc, r16, qq, acc);
        __syncthreads();
        if (t + 2 < 16) {
            dma16(agp1, a0a); dma16(agp2, a0b);
            dma16(bgp1, b0a); dma16(bgp2, b0b);
            agp1 += 32; agp2 += 32; bgp1 += 32; bgp2 += 32;
        }
        SCHED_FENCE();
        gemm_compute(As1, Bs1, wr, wc, r16, qq, acc);
        __syncthreads();
    }
}

// ---------------------------------------------------------------------------
// fused projections: bid<512 -> q ; <640 -> k ; else -> vT (LDS-transposed)
// ---------------------------------------------------------------------------
__global__ __launch_bounds__(256) void proj_all(const __bf16* __restrict__ qin,
                                                const __bf16* __restrict__ kin,
                                                const __bf16* __restrict__ vin,
                                                const __bf16* __restrict__ wtq,
                                                const __bf16* __restrict__ wtk,
                                                const __bf16* __restrict__ wtv,
                                                __bf16* __restrict__ qout,
                                                __bf16* __restrict__ kout,
                                                __bf16* __restrict__ vtout) {
    // pool: staging (4x4096=16384) during GEMM; 128x130 transpose tile after
    __shared__ __align__(16) __bf16 pool[16640];
    int bid = blockIdx.x;
    const __bf16 *A, *Bt;
    int mode, b;
    if (bid < 512)      { A = qin; Bt = wtq; mode = 0; b = bid; }
    else if (bid < 640) { A = kin; Bt = wtk; mode = 1; b = bid - 512; }
    else                { A = vin; Bt = wtv; mode = 2; b = bid - 640; }
    int row0 = (b >> 3) * 128, col0 = (b & 7) * 128;
    f32x4 acc[4][4] = {};
    gemm128(A, Bt, &pool[0], &pool[4096], &pool[8192], &pool[12288], row0, col0, acc);
    int tid = threadIdx.x;
    int lane = tid & 63, wave = tid >> 6;
    int r16 = lane & 15, qq = lane >> 4;
    int wr = wave >> 1, wc = wave & 1;
    if (mode < 2) {
#pragma unroll
        for (int i = 0; i < 4; i++)
#pragma unroll
            for (int j = 0; j < 4; j++)
#pragma unroll
                for (int rr = 0; rr < 4; rr++) {
                    int grow = row0 + wr * 64 + i * 16 + qq * 4 + rr;
                    int gcol = col0 + wc * 64 + j * 16 + r16;
                    int hh = gcol >> 6, d = gcol & 63;
                    __bf16 v = (__bf16)acc[i][j][rr];
                    if (mode == 0) {
                        int n = grow >> 11, qr = grow & 2047;
                        qout[((size_t)(n * HEADS + hh) * QLEN + qr) * HD + d] = v;
                    } else {
                        kout[((size_t)hh * KLEN + grow) * HD + d] = v;
                    }
                }
    } else {
        // transpose through LDS: row = local (hh,d) = gcol, col = local k = grow
#pragma unroll
        for (int i = 0; i < 4; i++)
#pragma unroll
            for (int j = 0; j < 4; j++) {
                int orow = wc * 64 + j * 16 + r16;
#pragma unroll
                for (int rr = 0; rr < 4; rr++) {
                    int ocol = wr * 64 + i * 16 + qq * 4 + rr;
                    pool[orow * 130 + ocol] = (__bf16)acc[i][j][rr];
                }
            }
        __syncthreads();
        int orow = tid >> 1, kh = (tid & 1) * 64;
        int hh = (col0 >> 6) + (orow >> 6), d = orow & 63;
        const __bf16* lp = &pool[orow * 130 + kh];
        __bf16* gp = vtout + ((size_t)hh * HD + d) * KLEN + row0 + kh;
#pragma unroll
        for (int jj = 0; jj < 8; jj++)
            *(uint4*)&gp[jj * 8] = *(const uint4*)&lp[jj * 8];
    }
}

// ---------------------------------------------------------------------------
// attention tile compute: S seeded from zro (no per-tile zero-init), mask as
// global floats applied multiplicatively post-exp, packed bf16 P.
// ---------------------------------------------------------------------------
__device__ __forceinline__ void attn_tile(const __bf16* ksb, const __bf16* vsb,
                                          const float* __restrict__ mrow,
                                          const bf16x8 (&qfrag)[4], const f32x16& zro,
                                          int col, int h,
                                          f32x16& o0, f32x16& o1, float2& rsl) {
    uint4 pf[4];
#pragma unroll
    for (int kt2 = 0; kt2 < 2; kt2++) {
        int R = kt2 * 32 + col;
        f32x16 s;
        {
            int cc = h ^ (R & 7);
            bf16x8 kf = *(const bf16x8*)&ksb[(R * 8 + cc) * 8];
            s = __builtin_amdgcn_mfma_f32_32x32x16_bf16(kf, qfrag[0], zro, 0, 0, 0);
        }
#pragma unroll
        for (int c = 1; c < 4; c++) {
            int cc = (2 * c + h) ^ (R & 7);
            bf16x8 kf = *(const bf16x8*)&ksb[(R * 8 + cc) * 8];
            s = __builtin_amdgcn_mfma_f32_32x32x16_bf16(kf, qfrag[c], s, 0, 0, 0);
        }
#pragma unroll
        for (int G = 0; G < 4; G++) {
            f32x4 mv = *(const f32x4*)&mrow[kt2 * 32 + 16 * (G >> 1) + 8 * h + 4 * (G & 1)];
            float p0 = fexp2(s[4 * G + 0]) * mv[0];
            float p1 = fexp2(s[4 * G + 1]) * mv[1];
            float p2 = fexp2(s[4 * G + 2]) * mv[2];
            float p3 = fexp2(s[4 * G + 3]) * mv[3];
            rsl.x += p0 + p2;
            rsl.y += p1 + p3;
            unsigned lo = pack_bf16(p0, p1), hi = pack_bf16(p2, p3);
            int ci = 2 * kt2 + (G >> 1);
            if ((G & 1) == 0) { pf[ci].x = lo; pf[ci].y = hi; }
            else              { pf[ci].z = lo; pf[ci].w = hi; }
        }
    }
#pragma unroll
    for (int c = 0; c < 4; c++) {
        int cc = (2 * c + h) ^ (col & 7);
        bf16x8 v0 = *(const bf16x8*)&vsb[(col * 8 + cc) * 8];
        bf16x8 v1 = *(const bf16x8*)&vsb[((32 + col) * 8 + cc) * 8];
        bf16x8 pb = __builtin_bit_cast(bf16x8, pf[c]);
        o0 = __builtin_amdgcn_mfma_f32_32x32x16_bf16(v0, pb, o0, 0, 0, 0);
        o1 = __builtin_amdgcn_mfma_f32_32x32x16_bf16(v1, pb, o1, 0, 0, 0);
    }
}

// ---------------------------------------------------------------------------
// fused flash attention v6. grid = (QLEN/128, HEADS, N), block 256.
// ---------------------------------------------------------------------------
__global__ __launch_bounds__(256, 4) void attn_kernel(const __bf16* __restrict__ qb,
                                                      const __bf16* __restrict__ kb,
                                                      const __bf16* __restrict__ vtb,
                                                      const float* __restrict__ mskf,
                                                      float* __restrict__ out) {
    __shared__ __align__(16) __bf16 ks[2][4096];
    __shared__ __align__(16) __bf16 vs[2][4096];

    int tid = threadIdx.x, wave = tid >> 6, lane = tid & 63;
    int col = lane & 31, h = lane >> 5;
    int q0 = blockIdx.x * 128, hh = blockIdx.y, n = blockIdx.z;
    const __bf16* qg = qb + ((size_t)(n * HEADS + hh) * QLEN + q0 + wave * 32 + col) * HD;
    const __bf16* kg = kb + (size_t)hh * KLEN * HD;
    const __bf16* vg = vtb + (size_t)hh * HD * KLEN;
    const float* mbase = mskf + n * KLEN;

    bf16x8 qfrag[4];
#pragma unroll
    for (int c = 0; c < 4; c++) qfrag[c] = *(const bf16x8*)&qg[c * 16 + h * 8];

    // DMA slot assignment (phi on k rows, XOR chunk swizzle) — verified r4/r5
    int s1 = tid, R1 = s1 >> 3, c1 = (s1 & 7) ^ (R1 & 7);
    int s2 = tid + 256, R2 = s2 >> 3, c2 = (s2 & 7) ^ (R2 & 7);
    int g1 = (R1 & 0x33) | ((R1 & 4) << 1) | ((R1 & 8) >> 1);
    int g2 = (R2 & 0x33) | ((R2 & 4) << 1) | ((R2 & 8) >> 1);
    const __bf16* kgp1 = kg + g1 * HD + c1 * 8;
    const __bf16* kgp2 = kg + g2 * HD + c2 * 8;
    const __bf16* vgp1 = vg + (size_t)R1 * KLEN + c1 * 8;
    const __bf16* vgp2 = vg + (size_t)R2 * KLEN + c2 * 8;
    __bf16 *kl0a = &ks[0][wave * 512], *kl0b = &ks[0][2048 + wave * 512];
    __bf16 *kl1a = &ks[1][wave * 512], *kl1b = &ks[1][2048 + wave * 512];
    __bf16 *vl0a = &vs[0][wave * 512], *vl0b = &vs[0][2048 + wave * 512];
    __bf16 *vl1a = &vs[1][wave * 512], *vl1b = &vs[1][2048 + wave * 512];

    dma16(kgp1, kl0a); dma16(kgp2, kl0b);
    dma16(vgp1, vl0a); dma16(vgp2, vl0b);
    kgp1 += 64 * HD; kgp2 += 64 * HD; vgp1 += 64; vgp2 += 64;
    __syncthreads();

    f32x16 o0 = {}, o1 = {};
    const f32x16 zro = {};
    float2 rsl = {0.f, 0.f};

    for (int t = 0; t < 32; t += 2) {
        dma16(kgp1, kl1a); dma16(kgp2, kl1b);
        dma16(vgp1, vl1a); dma16(vgp2, vl1b);
        kgp1 += 64 * HD; kgp2 += 64 * HD; vgp1 += 64; vgp2 += 64;
        SCHED_FENCE();
        attn_tile(ks[0], vs[0], mbase + t * 64, qfrag, zro, col, h, o0, o1, rsl);
        __syncthreads();
        if (t + 2 < 32) {
            dma16(kgp1, kl0a); dma16(kgp2, kl0b);
            dma16(vgp1, vl0a); dma16(vgp2, vl0b);
            kgp1 += 64 * HD; kgp2 += 64 * HD; vgp1 += 64; vgp2 += 64;
        }
        SCHED_FENCE();
        attn_tile(ks[1], vs[1], mbase + (t + 1) * 64, qfrag, zro, col, h, o0, o1, rsl);
        __syncthreads();
    }

    float r = rsl.x + rsl.y;
    r += __shfl_xor(r, 32);
    float inv = 1.0f / r;
    float* op = out + ((size_t)n * QLEN + q0 + wave * 32 + col) * EMBED + hh * HD;
#pragma unroll
    for (int G = 0; G < 4; G++) {
        float4 t0, t1;
        t0.x = o0[4 * G + 0] * inv; t0.y = o0[4 * G + 1] * inv;
        t0.z = o0[4 * G + 2] * inv; t0.w = o0[4 * G + 3] * inv;
        t1.x = o1[4 * G + 0] * inv; t1.y = o1[4 * G + 1] * inv;
        t1.z = o1[4 * G + 2] * inv; t1.w = o1[4 * G + 3] * inv;
        *(float4*)&op[8 * G + 4 * h] = t0;
        *(float4*)&op[32 + 8 * G + 4 * h] = t1;
    }
}

// ---------------------------------------------------------------------------
extern "C" void kernel_launch(void* const* d_in, const int* in_sizes, int n_in,
                              void* d_out, int out_size, void* d_ws, size_t ws_size,
                              hipStream_t stream) {
    const float* queries = (const float*)d_in[0];
    const float* keys    = (const float*)d_in[1];
    const float* values  = (const float*)d_in[2];
    const int*   mask    = (const int*)d_in[3];
    const float* Wq      = (const float*)d_in[4];
    const float* Wk      = (const float*)d_in[5];
    const float* Wv      = (const float*)d_in[6];
    float* out = (float*)d_out;

    const size_t MiB = 1048576;
    char* ws = (char*)d_ws;
    __bf16* qbf   = (__bf16*)(ws);             // 16 MiB  q   [N][H][Q][64] (pre-scaled)
    __bf16* kbf   = (__bf16*)(ws + 16 * MiB);  //  4 MiB  k   [H][K][64]
    __bf16* vtbf  = (__bf16*)(ws + 20 * MiB);  //  4 MiB  vT  [H][64][K]
    __bf16* wtq   = (__bf16*)(ws + 24 * MiB);  //  1 MiB
    __bf16* wtk   = (__bf16*)(ws + 25 * MiB);
    __bf16* wtv   = (__bf16*)(ws + 26 * MiB);
    __bf16* qin   = (__bf16*)(ws + 27 * MiB);  //  8 MiB
    __bf16* kin   = (__bf16*)(ws + 35 * MiB);  //  2 MiB
    __bf16* vin   = (__bf16*)(ws + 37 * MiB);  //  2 MiB
    float*  mskf  = (float*)(ws + 39 * MiB);   // 32 KiB mask floats

    prep<<<4612, 256, 0, stream>>>(queries, keys, values, Wq, Wk, Wv, mask,
                                   qin, kin, vin, wtq, wtk, wtv, mskf);
    proj_all<<<768, 256, 0, stream>>>(qin, kin, vin, wtq, wtk, wtv, qbf, kbf, vtbf);
    attn_kernel<<<dim3(QLEN / 128, HEADS, NB), 256, 0, stream>>>(qbf, kbf, vtbf, mskf, out);
}

// Round 7
// 204.326 us; speedup vs baseline: 1.0700x; 1.0700x over previous
//
#include <hip/hip_runtime.h>

#define NB 4
#define QLEN 2048
#define KLEN 2048
#define QDIM 512
#define EMBED 1024
#define HEADS 16
#define HD 64

typedef __bf16 bf16x8 __attribute__((ext_vector_type(8)));
typedef float f32x4 __attribute__((ext_vector_type(4)));
typedef float f32x16 __attribute__((ext_vector_type(16)));

#define CLOG 0.18033688011112042f   // 0.125 * log2(e), folded into Wq

// guaranteed-cheap exp2
__device__ __forceinline__ float fexp2(float x) {
#if __has_builtin(__builtin_amdgcn_exp2f)
    return __builtin_amdgcn_exp2f(x);
#else
    float r;
    asm("v_exp_f32 %0, %1\n\ts_nop 1" : "=v"(r) : "v"(x));
    return r;
#endif
}

// pack two f32 into packed bf16 (RNE)
#if __has_builtin(__builtin_amdgcn_cvt_pk_bf16_f32)
typedef __bf16 bf16x2_t __attribute__((ext_vector_type(2)));
__device__ __forceinline__ unsigned pack_bf16(float a, float b) {
    bf16x2_t r = __builtin_amdgcn_cvt_pk_bf16_f32(a, b);
    return __builtin_bit_cast(unsigned, r);
}
#else
__device__ __forceinline__ unsigned pack_bf16(float a, float b) {
    unsigned ua = __builtin_bit_cast(unsigned, a);
    unsigned ub = __builtin_bit_cast(unsigned, b);
    ua = (ua + 0x7FFFu + ((ua >> 16) & 1u)) >> 16;
    ub = (ub + 0x7FFFu + ((ub >> 16) & 1u)) & 0xFFFF0000u;
    return ua | ub;
}
#endif

#if __has_builtin(__builtin_amdgcn_sched_barrier)
#define SCHED_FENCE() __builtin_amdgcn_sched_barrier(0)
#else
#define SCHED_FENCE()
#endif

// async global->LDS 16B: dest = wave-uniform base + lane*16
__device__ __forceinline__ void dma16(const void* g, void* l) {
    __builtin_amdgcn_global_load_lds(
        (const __attribute__((address_space(1))) void*)g,
        (__attribute__((address_space(3))) void*)l, 16, 0, 0);
}

// ---------------------------------------------------------------------------
// prep: bf16 casts (q,k,v) + W transposes. 4608 blocks x 256.
// ---------------------------------------------------------------------------
__global__ __launch_bounds__(256) void prep(const float* __restrict__ q,
                                            const float* __restrict__ k,
                                            const float* __restrict__ v,
                                            const float* __restrict__ Wq,
                                            const float* __restrict__ Wk,
                                            const float* __restrict__ Wv,
                                            __bf16* __restrict__ qd,
                                            __bf16* __restrict__ kd,
                                            __bf16* __restrict__ vd,
                                            __bf16* __restrict__ WtQ,
                                            __bf16* __restrict__ WtK,
                                            __bf16* __restrict__ WtV) {
    __shared__ float tile[32][33];
    int b = blockIdx.x, tid = threadIdx.x;
    if (b < 3072) {
        const float* src; __bf16* dst; int cb;
        if (b < 2048)      { src = q; dst = qd; cb = b; }
        else if (b < 2560) { src = k; dst = kd; cb = b - 2048; }
        else               { src = v; dst = vd; cb = b - 2560; }
        int i = (cb * 256 + tid) * 8;
        float4 a0 = *(const float4*)&src[i];
        float4 a1 = *(const float4*)&src[i + 4];
        bf16x8 o;
        o[0] = (__bf16)a0.x; o[1] = (__bf16)a0.y; o[2] = (__bf16)a0.z; o[3] = (__bf16)a0.w;
        o[4] = (__bf16)a1.x; o[5] = (__bf16)a1.y; o[6] = (__bf16)a1.z; o[7] = (__bf16)a1.w;
        *(bf16x8*)&dst[i] = o;
    } else {
        int tb = b - 3072;
        int which = tb >> 9, r = tb & 511;
        const float* src = (which == 0) ? Wq : (which == 1) ? Wk : Wv;
        __bf16* dst = (which == 0) ? WtQ : (which == 1) ? WtK : WtV;
        float scale = (which == 0) ? CLOG : 1.0f;
        int e0 = (r & 31) * 32, c0 = (r >> 5) * 32;
        int tx = tid & 31, ty = tid >> 5;  // 32 x 8
        for (int i = 0; i < 4; i++)
            tile[ty + 8 * i][tx] = src[(c0 + ty + 8 * i) * EMBED + e0 + tx];
        __syncthreads();
        for (int i = 0; i < 4; i++)
            dst[(e0 + ty + 8 * i) * QDIM + c0 + tx] = (__bf16)(tile[tx][ty + 8 * i] * scale);
    }
}

// ---------------------------------------------------------------------------
// 128x128-tile GEMM body, double-buffered DMA staging, BK=32, 2x2 wave grid
// ---------------------------------------------------------------------------
__device__ __forceinline__ void gemm_compute(const __bf16* As, const __bf16* Bs,
                                             int wr, int wc, int r16, int qq,
                                             f32x4 (&acc)[4][4]) {
    bf16x8 af[4], bq[4];
#pragma unroll
    for (int i = 0; i < 4; i++)
        af[i] = *(const bf16x8*)&As[(wr * 64 + i * 16 + r16) * 32 + qq * 8];
#pragma unroll
    for (int j = 0; j < 4; j++)
        bq[j] = *(const bf16x8*)&Bs[(wc * 64 + j * 16 + r16) * 32 + qq * 8];
#pragma unroll
    for (int i = 0; i < 4; i++)
#pragma unroll
        for (int j = 0; j < 4; j++)
            acc[i][j] = __builtin_amdgcn_mfma_f32_16x16x32_bf16(af[i], bq[j], acc[i][j], 0, 0, 0);
}

__device__ __forceinline__ void gemm128(const __bf16* __restrict__ A,
                                        const __bf16* __restrict__ Bt,
                                        __bf16* As0, __bf16* As1,
                                        __bf16* Bs0, __bf16* Bs1,
                                        int row0, int col0, f32x4 (&acc)[4][4]) {
    int tid = threadIdx.x, wave = tid >> 6, lane = tid & 63;
    int r16 = lane & 15, qq = lane >> 4;
    int wr = wave >> 1, wc = wave & 1;
    const __bf16* agp1 = A + (size_t)(row0 + (tid >> 2)) * QDIM + (tid & 3) * 8;
    const __bf16* agp2 = A + (size_t)(row0 + 64 + (tid >> 2)) * QDIM + (tid & 3) * 8;
    const __bf16* bgp1 = Bt + (size_t)(col0 + (tid >> 2)) * QDIM + (tid & 3) * 8;
    const __bf16* bgp2 = Bt + (size_t)(col0 + 64 + (tid >> 2)) * QDIM + (tid & 3) * 8;
    __bf16 *a0a = &As0[wave * 512], *a0b = &As0[2048 + wave * 512];
    __bf16 *a1a = &As1[wave * 512], *a1b = &As1[2048 + wave * 512];
    __bf16 *b0a = &Bs0[wave * 512], *b0b = &Bs0[2048 + wave * 512];
    __bf16 *b1a = &Bs1[wave * 512], *b1b = &Bs1[2048 + wave * 512];

    dma16(agp1, a0a); dma16(agp2, a0b);
    dma16(bgp1, b0a); dma16(bgp2, b0b);
    agp1 += 32; agp2 += 32; bgp1 += 32; bgp2 += 32;
    __syncthreads();

    for (int t = 0; t < 16; t += 2) {
        dma16(agp1, a1a); dma16(agp2, a1b);
        dma16(bgp1, b1a); dma16(bgp2, b1b);
        agp1 += 32; agp2 += 32; bgp1 += 32; bgp2 += 32;
        SCHED_FENCE();
        gemm_compute(As0, Bs0, wr, wc, r16, qq, acc);
        __syncthreads();
        if (t + 2 < 16) {
            dma16(agp1, a0a); dma16(agp2, a0b);
            dma16(bgp1, b0a); dma16(bgp2, b0b);
            agp1 += 32; agp2 += 32; bgp1 += 32; bgp2 += 32;
        }
        SCHED_FENCE();
        gemm_compute(As1, Bs1, wr, wc, r16, qq, acc);
        __syncthreads();
    }
}

// ---------------------------------------------------------------------------
// fused projections: all modes epilogue via LDS tile -> coalesced 128B stores
// bid<512 -> q ; <640 -> k ; else -> vT
// ---------------------------------------------------------------------------
__global__ __launch_bounds__(256) void proj_all(const __bf16* __restrict__ qin,
                                                const __bf16* __restrict__ kin,
                                                const __bf16* __restrict__ vin,
                                                const __bf16* __restrict__ wtq,
                                                const __bf16* __restrict__ wtk,
                                                const __bf16* __restrict__ wtv,
                                                __bf16* __restrict__ qout,
                                                __bf16* __restrict__ kout,
                                                __bf16* __restrict__ vtout) {
    // pool: 4 staging buffers (16384) during GEMM; 128x130 tile after
    __shared__ __align__(16) __bf16 pool[16640];
    int bid = blockIdx.x;
    const __bf16 *A, *Bt;
    int mode, b;
    if (bid < 512)      { A = qin; Bt = wtq; mode = 0; b = bid; }
    else if (bid < 640) { A = kin; Bt = wtk; mode = 1; b = bid - 512; }
    else                { A = vin; Bt = wtv; mode = 2; b = bid - 640; }
    int row0 = (b >> 3) * 128, col0 = (b & 7) * 128;
    f32x4 acc[4][4] = {};
    gemm128(A, Bt, &pool[0], &pool[4096], &pool[8192], &pool[12288], row0, col0, acc);
    int tid = threadIdx.x;
    int lane = tid & 63, wave = tid >> 6;
    int r16 = lane & 15, qq = lane >> 4;
    int wr = wave >> 1, wc = wave & 1;
    // stage C tile into LDS (mode<2: [row][col]; mode 2: transposed)
#pragma unroll
    for (int i = 0; i < 4; i++)
#pragma unroll
        for (int j = 0; j < 4; j++) {
            int cl = wc * 64 + j * 16 + r16;
#pragma unroll
            for (int rr = 0; rr < 4; rr++) {
                int rl = wr * 64 + i * 16 + qq * 4 + rr;
                int orow = (mode < 2) ? rl : cl;
                int ocol = (mode < 2) ? cl : rl;
                pool[orow * 130 + ocol] = (__bf16)acc[i][j][rr];
            }
        }
    __syncthreads();
    // coalesced store: thread -> (row = tid>>1, 64-col half = tid&1)
    int row = tid >> 1, half = tid & 1;
    const __bf16* lp = &pool[row * 130 + half * 64];
    __bf16* gp;
    if (mode == 0) {
        int grow = row0 + row, gcol = col0 + half * 64;
        int n = grow >> 11, qr = grow & 2047, hh = gcol >> 6;
        gp = qout + ((size_t)(n * HEADS + hh) * QLEN + qr) * HD;
    } else if (mode == 1) {
        int grow = row0 + row, gcol = col0 + half * 64;
        int hh = gcol >> 6;
        gp = kout + ((size_t)hh * KLEN + grow) * HD;
    } else {
        int gcol = col0 + row;           // (hh, d)
        int hh = gcol >> 6, d = gcol & 63;
        gp = vtout + ((size_t)hh * HD + d) * KLEN + row0 + half * 64;
    }
#pragma unroll
    for (int jj = 0; jj < 8; jj++)
        *(uint4*)&gp[jj * 8] = *(const uint4*)&lp[jj * 8];
}

// ---------------------------------------------------------------------------
// attention tile compute: wave owns 64 q (two 32-q B-frag subtiles); K/V/mask
// LDS reads shared across both subtiles. S seeded from zro; mask multiplicative
// from LDS (loaded once per block); packed bf16 P.
// ---------------------------------------------------------------------------
__device__ __forceinline__ void attn_tile(const __bf16* ksb, const __bf16* vsb,
                                          const float* mrow,
                                          const bf16x8 (&qfrag)[2][4], const f32x16& zro,
                                          int col, int h,
                                          f32x16 (&o)[2][2], float2 (&rsl)[2]) {
    uint4 pf[2][4];
#pragma unroll
    for (int kt2 = 0; kt2 < 2; kt2++) {
        int R = kt2 * 32 + col;
        bf16x8 kf[4];
#pragma unroll
        for (int c = 0; c < 4; c++) {
            int cc = (2 * c + h) ^ (R & 7);
            kf[c] = *(const bf16x8*)&ksb[(R * 8 + cc) * 8];
        }
        f32x16 s0 = __builtin_amdgcn_mfma_f32_32x32x16_bf16(kf[0], qfrag[0][0], zro, 0, 0, 0);
        f32x16 s1 = __builtin_amdgcn_mfma_f32_32x32x16_bf16(kf[0], qfrag[1][0], zro, 0, 0, 0);
#pragma unroll
        for (int c = 1; c < 4; c++) {
            s0 = __builtin_amdgcn_mfma_f32_32x32x16_bf16(kf[c], qfrag[0][c], s0, 0, 0, 0);
            s1 = __builtin_amdgcn_mfma_f32_32x32x16_bf16(kf[c], qfrag[1][c], s1, 0, 0, 0);
        }
#pragma unroll
        for (int G = 0; G < 4; G++) {
            f32x4 mv = *(const f32x4*)&mrow[kt2 * 32 + 16 * (G >> 1) + 8 * h + 4 * (G & 1)];
            int ci = 2 * kt2 + (G >> 1);
            {
                float p0 = fexp2(s0[4 * G + 0]) * mv[0];
                float p1 = fexp2(s0[4 * G + 1]) * mv[1];
                float p2 = fexp2(s0[4 * G + 2]) * mv[2];
                float p3 = fexp2(s0[4 * G + 3]) * mv[3];
                rsl[0].x += p0 + p2; rsl[0].y += p1 + p3;
                unsigned lo = pack_bf16(p0, p1), hi = pack_bf16(p2, p3);
                if ((G & 1) == 0) { pf[0][ci].x = lo; pf[0][ci].y = hi; }
                else              { pf[0][ci].z = lo; pf[0][ci].w = hi; }
            }
            {
                float p0 = fexp2(s1[4 * G + 0]) * mv[0];
                float p1 = fexp2(s1[4 * G + 1]) * mv[1];
                float p2 = fexp2(s1[4 * G + 2]) * mv[2];
                float p3 = fexp2(s1[4 * G + 3]) * mv[3];
                rsl[1].x += p0 + p2; rsl[1].y += p1 + p3;
                unsigned lo = pack_bf16(p0, p1), hi = pack_bf16(p2, p3);
                if ((G & 1) == 0) { pf[1][ci].x = lo; pf[1][ci].y = hi; }
                else              { pf[1][ci].z = lo; pf[1][ci].w = hi; }
            }
        }
    }
#pragma unroll
    for (int c = 0; c < 4; c++) {
        int cc = (2 * c + h) ^ (col & 7);
        bf16x8 v0 = *(const bf16x8*)&vsb[(col * 8 + cc) * 8];
        bf16x8 v1 = *(const bf16x8*)&vsb[((32 + col) * 8 + cc) * 8];
        bf16x8 pb0 = __builtin_bit_cast(bf16x8, pf[0][c]);
        bf16x8 pb1 = __builtin_bit_cast(bf16x8, pf[1][c]);
        o[0][0] = __builtin_amdgcn_mfma_f32_32x32x16_bf16(v0, pb0, o[0][0], 0, 0, 0);
        o[1][0] = __builtin_amdgcn_mfma_f32_32x32x16_bf16(v1, pb0, o[1][0], 0, 0, 0);
        o[0][1] = __builtin_amdgcn_mfma_f32_32x32x16_bf16(v0, pb1, o[0][1], 0, 0, 0);
        o[1][1] = __builtin_amdgcn_mfma_f32_32x32x16_bf16(v1, pb1, o[1][1], 0, 0, 0);
    }
}

// ---------------------------------------------------------------------------
// fused flash attention v7: 256 q per block (wave owns 64 q).
// grid = (QLEN/256, HEADS, N), block 256.
// ---------------------------------------------------------------------------
__global__ __launch_bounds__(256, 2) void attn_kernel(const __bf16* __restrict__ qb,
                                                      const __bf16* __restrict__ kb,
                                                      const __bf16* __restrict__ vtb,
                                                      const int* __restrict__ mask,
                                                      float* __restrict__ out) {
    __shared__ __align__(16) __bf16 ks[2][4096];
    __shared__ __align__(16) __bf16 vs[2][4096];
    __shared__ __align__(16) float msf[KLEN];

    int tid = threadIdx.x, wave = tid >> 6, lane = tid & 63;
    int col = lane & 31, h = lane >> 5;
    int q0 = blockIdx.x * 256, hh = blockIdx.y, n = blockIdx.z;
    const __bf16* qg = qb + ((size_t)(n * HEADS + hh) * QLEN + q0 + wave * 64 + col) * HD;
    const __bf16* kg = kb + (size_t)hh * KLEN * HD;
    const __bf16* vg = vtb + (size_t)hh * HD * KLEN;
    const int* mg = mask + n * KLEN;

    // Q^T B-frags straight from global: two 32-q subtiles per wave
    bf16x8 qfrag[2][4];
#pragma unroll
    for (int u = 0; u < 2; u++)
#pragma unroll
        for (int c = 0; c < 4; c++)
            qfrag[u][c] = *(const bf16x8*)&qg[(size_t)u * 32 * HD + c * 16 + h * 8];

    // DMA slot assignment (phi on k rows, XOR chunk swizzle) — verified r4-r6
    int s1 = tid, R1 = s1 >> 3, c1 = (s1 & 7) ^ (R1 & 7);
    int s2 = tid + 256, R2 = s2 >> 3, c2 = (s2 & 7) ^ (R2 & 7);
    int g1 = (R1 & 0x33) | ((R1 & 4) << 1) | ((R1 & 8) >> 1);
    int g2 = (R2 & 0x33) | ((R2 & 4) << 1) | ((R2 & 8) >> 1);
    const __bf16* kgp1 = kg + g1 * HD + c1 * 8;
    const __bf16* kgp2 = kg + g2 * HD + c2 * 8;
    const __bf16* vgp1 = vg + (size_t)R1 * KLEN + c1 * 8;
    const __bf16* vgp2 = vg + (size_t)R2 * KLEN + c2 * 8;
    __bf16 *kl0a = &ks[0][wave * 512], *kl0b = &ks[0][2048 + wave * 512];
    __bf16 *kl1a = &ks[1][wave * 512], *kl1b = &ks[1][2048 + wave * 512];
    __bf16 *vl0a = &vs[0][wave * 512], *vl0b = &vs[0][2048 + wave * 512];
    __bf16 *vl1a = &vs[1][wave * 512], *vl1b = &vs[1][2048 + wave * 512];

    // prologue: DMA tile 0 -> buf0; mask -> LDS once (multiplicative floats)
    dma16(kgp1, kl0a); dma16(kgp2, kl0b);
    dma16(vgp1, vl0a); dma16(vgp2, vl0b);
    kgp1 += 64 * HD; kgp2 += 64 * HD; vgp1 += 64; vgp2 += 64;
    {
        int i8 = tid * 8;
        int4 ma = *(const int4*)&mg[i8];
        int4 mb = *(const int4*)&mg[i8 + 4];
        f32x4 fa, fb;
        fa[0] = ma.x ? 1.f : 0.f; fa[1] = ma.y ? 1.f : 0.f;
        fa[2] = ma.z ? 1.f : 0.f; fa[3] = ma.w ? 1.f : 0.f;
        fb[0] = mb.x ? 1.f : 0.f; fb[1] = mb.y ? 1.f : 0.f;
        fb[2] = mb.z ? 1.f : 0.f; fb[3] = mb.w ? 1.f : 0.f;
        *(f32x4*)&msf[i8] = fa;
        *(f32x4*)&msf[i8 + 4] = fb;
    }
    __syncthreads();

    f32x16 o[2][2] = {};
    const f32x16 zro = {};
    float2 rsl[2] = {{0.f, 0.f}, {0.f, 0.f}};

    for (int t = 0; t < 32; t += 2) {
        dma16(kgp1, kl1a); dma16(kgp2, kl1b);
        dma16(vgp1, vl1a); dma16(vgp2, vl1b);
        kgp1 += 64 * HD; kgp2 += 64 * HD; vgp1 += 64; vgp2 += 64;
        SCHED_FENCE();
        attn_tile(ks[0], vs[0], &msf[t * 64], qfrag, zro, col, h, o, rsl);
        __syncthreads();
        if (t + 2 < 32) {
            dma16(kgp1, kl0a); dma16(kgp2, kl0b);
            dma16(vgp1, vl0a); dma16(vgp2, vl0b);
            kgp1 += 64 * HD; kgp2 += 64 * HD; vgp1 += 64; vgp2 += 64;
        }
        SCHED_FENCE();
        attn_tile(ks[1], vs[1], &msf[(t + 1) * 64], qfrag, zro, col, h, o, rsl);
        __syncthreads();
    }

    // epilogue: lane owns q-cols q0 + wave*64 + u*32 + col
#pragma unroll
    for (int u = 0; u < 2; u++) {
        float r = rsl[u].x + rsl[u].y;
        r += __shfl_xor(r, 32);
        float inv = 1.0f / r;
        float* op = out + ((size_t)n * QLEN + q0 + wave * 64 + u * 32 + col) * EMBED + hh * HD;
#pragma unroll
        for (int G = 0; G < 4; G++) {
            float4 t0, t1;
            t0.x = o[0][u][4 * G + 0] * inv; t0.y = o[0][u][4 * G + 1] * inv;
            t0.z = o[0][u][4 * G + 2] * inv; t0.w = o[0][u][4 * G + 3] * inv;
            t1.x = o[1][u][4 * G + 0] * inv; t1.y = o[1][u][4 * G + 1] * inv;
            t1.z = o[1][u][4 * G + 2] * inv; t1.w = o[1][u][4 * G + 3] * inv;
            *(float4*)&op[8 * G + 4 * h] = t0;
            *(float4*)&op[32 + 8 * G + 4 * h] = t1;
        }
    }
}

// ---------------------------------------------------------------------------
extern "C" void kernel_launch(void* const* d_in, const int* in_sizes, int n_in,
                              void* d_out, int out_size, void* d_ws, size_t ws_size,
                              hipStream_t stream) {
    const float* queries = (const float*)d_in[0];
    const float* keys    = (const float*)d_in[1];
    const float* values  = (const float*)d_in[2];
    const int*   mask    = (const int*)d_in[3];
    const float* Wq      = (const float*)d_in[4];
    const float* Wk      = (const float*)d_in[5];
    const float* Wv      = (const float*)d_in[6];
    float* out = (float*)d_out;

    const size_t MiB = 1048576;
    char* ws = (char*)d_ws;
    __bf16* qbf   = (__bf16*)(ws);             // 16 MiB  q   [N][H][Q][64] (pre-scaled)
    __bf16* kbf   = (__bf16*)(ws + 16 * MiB);  //  4 MiB  k   [H][K][64]
    __bf16* vtbf  = (__bf16*)(ws + 20 * MiB);  //  4 MiB  vT  [H][64][K]
    __bf16* wtq   = (__bf16*)(ws + 24 * MiB);  //  1 MiB
    __bf16* wtk   = (__bf16*)(ws + 25 * MiB);
    __bf16* wtv   = (__bf16*)(ws + 26 * MiB);
    __bf16* qin   = (__bf16*)(ws + 27 * MiB);  //  8 MiB
    __bf16* kin   = (__bf16*)(ws + 35 * MiB);  //  2 MiB
    __bf16* vin   = (__bf16*)(ws + 37 * MiB);  //  2 MiB

    prep<<<4608, 256, 0, stream>>>(queries, keys, values, Wq, Wk, Wv,
                                   qin, kin, vin, wtq, wtk, wtv);
    proj_all<<<768, 256, 0, stream>>>(qin, kin, vin, wtq, wtk, wtv, qbf, kbf, vtbf);
    attn_kernel<<<dim3(QLEN / 256, HEADS, NB), 256, 0, stream>>>(qbf, kbf, vtbf, mask, out);
}